// Round 13
// baseline (414.625 us; speedup 1.0000x reference)
//
#include <hip/hip_runtime.h>
#include <math.h>

#define NN 50000
#define NE 500000
#define NRB 196   // (NN+255)/256 row blocks per GEMM (BM=256)
// D_IN=128, D_H=256, D_C=768, D_OUT=40

typedef __attribute__((ext_vector_type(8))) short short8;   // 8 bf16 (4 VGPRs)
typedef __attribute__((ext_vector_type(4))) float f32x4;    // MFMA acc

__device__ __forceinline__ float leaky02(float x) { return x > 0.f ? x : 0.2f * x; }
__device__ __forceinline__ ushort f2b(float f) {
    uint u = __float_as_uint(f);
    u += 0x7fffu + ((u >> 16) & 1u);          // RNE
    return (ushort)(u >> 16);
}
__device__ __forceinline__ float b2f(ushort h) { return __uint_as_float(((uint)h) << 16); }
__device__ __forceinline__ float b2f_lo(uint w) { return __uint_as_float(w << 16); }
__device__ __forceinline__ float b2f_hi(uint w) { return __uint_as_float(w & 0xffff0000u); }
__device__ __forceinline__ uint pack2(float a, float b) {
    return (uint)f2b(a) | ((uint)f2b(b) << 16);
}

// ---------------- all weight transposes in one launch: W [K][256] fp32 -> Wt [256][K] bf16 ----------------
__global__ void mm_wt_all(const float* __restrict__ Wg, const float* __restrict__ Wi1,
                          const float* __restrict__ Wi2, const float* __restrict__ Wc,
                          const float* __restrict__ Wl,
                          ushort* __restrict__ tg, ushort* __restrict__ ti1,
                          ushort* __restrict__ ti2, ushort* __restrict__ tc,
                          ushort* __restrict__ tl)
{
    int idx = blockIdx.x * 256 + threadIdx.x;
    const float* W; ushort* T; int K; int base;
    if (idx < 32768)       { W = Wg;  T = tg;  K = 128; base = 0; }
    else if (idx < 65536)  { W = Wi1; T = ti1; K = 128; base = 32768; }
    else if (idx < 131072) { W = Wi2; T = ti2; K = 256; base = 65536; }
    else if (idx < 163840) { W = Wc;  T = tc;  K = 128; base = 131072; }
    else if (idx < 360448) { W = Wl;  T = tl;  K = 768; base = 163840; }
    else return;
    int i = idx - base;
    int n = i / K, k = i - n * K;
    T[i] = f2b(W[(size_t)k * 256 + n]);
}

// ---------------- va = W_gat @ att_src, vd = W_gat @ att_dst (both [128]) ----------------
__global__ void mm_attvec(const float* __restrict__ W, const float* __restrict__ as_,
                          const float* __restrict__ ad_, float* __restrict__ va, float* __restrict__ vd)
{
    int i = threadIdx.x;           // 0..255
    const float* vec = (i < 128) ? as_ : ad_;
    int k = i & 127;
    float s = 0.f;
    for (int j = 0; j < 256; ++j) s += W[(size_t)k * 256 + j] * vec[j];
    if (i < 128) va[k] = s; else vd[k] = s;
}

// ---------------- fused: x fp32 -> xb bf16, es/ed = x.va / x.vd (wave per node) ----------------
__global__ __launch_bounds__(256) void mm_cvt_es(const float* __restrict__ x,
                                                 const float* __restrict__ va, const float* __restrict__ vd,
                                                 ushort* __restrict__ xb,
                                                 float* __restrict__ es, float* __restrict__ ed)
{
    int node = blockIdx.x * 4 + (threadIdx.x >> 6);
    int lane = threadIdx.x & 63;
    if (node >= NN) return;
    float2 xv = *(const float2*)(x + (size_t)node * 128 + lane * 2);
    float2 a = *(const float2*)(va + lane * 2);
    float2 b = *(const float2*)(vd + lane * 2);
    *(uint*)(xb + (size_t)node * 128 + lane * 2) = pack2(xv.x, xv.y);
    float s = xv.x * a.x + xv.y * a.y;
    float d = xv.x * b.x + xv.y * b.y;
    #pragma unroll
    for (int off = 32; off; off >>= 1) {
        s += __shfl_down(s, off);
        d += __shfl_down(d, off);
    }
    if (lane == 0) { es[node] = s; ed[node] = d; }
}

// ---------------- CSR build: count -> 3-phase scan -> fill ----------------
__global__ void mm_count(const int* __restrict__ dst, int* __restrict__ deg)
{
    int e = blockIdx.x * 256 + threadIdx.x;
    if (e >= NE) return;
    atomicAdd(&deg[dst[e]], 1);
}

__global__ __launch_bounds__(256) void mm_scan1(const int* __restrict__ deg, int* __restrict__ part)
{
    __shared__ int red[256];
    int i = blockIdx.x * 256 + threadIdx.x;
    red[threadIdx.x] = (i < NN) ? deg[i] : 0;
    __syncthreads();
    for (int off = 128; off; off >>= 1) {
        if (threadIdx.x < off) red[threadIdx.x] += red[threadIdx.x + off];
        __syncthreads();
    }
    if (threadIdx.x == 0) part[blockIdx.x] = red[0];
}

__global__ __launch_bounds__(256) void mm_scan2(int* __restrict__ part, int nb)
{
    __shared__ int tile[256];
    int t = threadIdx.x;
    int v = (t < nb) ? part[t] : 0;
    tile[t] = v; __syncthreads();
    for (int off = 1; off < 256; off <<= 1) {
        int a = (t >= off) ? tile[t - off] : 0;
        __syncthreads();
        tile[t] += a;
        __syncthreads();
    }
    if (t < nb) part[t] = tile[t] - v;   // exclusive
}

__global__ __launch_bounds__(256) void mm_scan3(const int* __restrict__ deg, const int* __restrict__ part,
                                                int* __restrict__ row_ptr, int* __restrict__ cursor)
{
    __shared__ int tile[256];
    int t = threadIdx.x;
    int i = blockIdx.x * 256 + t;
    int v = (i < NN) ? deg[i] : 0;
    tile[t] = v; __syncthreads();
    for (int off = 1; off < 256; off <<= 1) {
        int a = (t >= off) ? tile[t - off] : 0;
        __syncthreads();
        tile[t] += a;
        __syncthreads();
    }
    if (i < NN) {
        int ex = part[blockIdx.x] + tile[t] - v;
        row_ptr[i] = ex;
        cursor[i] = ex;
    }
    if (i == 0) row_ptr[NN] = NE;
}

__global__ void mm_fill(const int* __restrict__ src, const int* __restrict__ dst,
                        int* __restrict__ cursor, int* __restrict__ csr_src)
{
    int e = blockIdx.x * 256 + threadIdx.x;
    if (e >= NE) return;
    int pos = atomicAdd(&cursor[dst[e]], 1);
    csr_src[pos] = src[e];
}

__global__ void mm_dis(const int* __restrict__ row_ptr, float* __restrict__ dis)
{
    int i = blockIdx.x * 256 + threadIdx.x;
    if (i >= NN) return;
    dis[i] = rsqrtf((float)(row_ptr[i + 1] - row_ptr[i] + 1));
}

// ---------------- fused per-node: in-reg segment sort (determinism) + GAT softmax + 3-way gather ----------------
__global__ __launch_bounds__(256) void mm_node_agg(
    const int* __restrict__ row_ptr, const int* __restrict__ csr_src,
    const float* __restrict__ es, const float* __restrict__ ed,
    const float* __restrict__ dis,
    const ushort* __restrict__ xb, ushort* __restrict__ aggb)
{
    int d = blockIdx.x * 4 + (threadIdx.x >> 6);
    int lane = threadIdx.x & 63;
    if (d >= NN) return;
    int start = row_ptr[d], end = row_ptr[d + 1];
    int deg = end - start;
    float edd = ed[d], disd = dis[d];
    float selfv = leaky02(es[d] + edd);

    int myidx = (start + lane < end) ? csr_src[start + lane] : 0x7fffffff;
    if (deg <= 64) {
        #pragma unroll
        for (int k = 2; k <= 64; k <<= 1) {
            #pragma unroll
            for (int j = k >> 1; j > 0; j >>= 1) {
                int o = __shfl_xor(myidx, j);
                bool keepmin = (((lane & k) == 0) == ((lane & j) == 0));
                myidx = keepmin ? min(myidx, o) : max(myidx, o);
            }
        }
    }
    bool valid = (lane < deg);
    float myl = -3.0e38f, mynw = 0.f;
    if (valid) {
        myl = leaky02(es[myidx] + edd);
        mynw = dis[myidx] * disd;
    }
    float lmax = fmaxf(selfv, myl);
    for (int e = start + 64 + lane; e < end; e += 64)
        lmax = fmaxf(lmax, leaky02(es[csr_src[e]] + edd));
    #pragma unroll
    for (int off = 1; off < 64; off <<= 1) lmax = fmaxf(lmax, __shfl_xor(lmax, off));
    float m = lmax;

    float lsum = valid ? __expf(myl - m) : 0.f;
    if (lane == 0) lsum += __expf(selfv - m);
    for (int e = start + 64 + lane; e < end; e += 64)
        lsum += __expf(leaky02(es[csr_src[e]] + edd) - m);
    #pragma unroll
    for (int off = 1; off < 64; off <<= 1) lsum += __shfl_xor(lsum, off);
    float inv = 1.f / lsum;
    float myal = __expf(myl - m) * inv;

    float aself = __expf(selfv - m) * inv;
    float d2 = disd * disd;
    uint wself = *(const uint*)(xb + (size_t)d * 128 + lane * 2);
    float x0 = b2f_lo(wself), x1 = b2f_hi(wself);
    float gat0 = aself * x0, gat1 = aself * x1;
    float gin0 = x0, gin1 = x1;
    float gcn0 = d2 * x0, gcn1 = d2 * x1;

    for (int base = start; base < end; base += 64) {
        int cnt = min(64, end - base);
        int bidx; float bal, bnw;
        if (base == start) { bidx = myidx; bal = myal; bnw = mynw; }
        else {
            bidx = -1; bal = 0.f; bnw = 0.f;
            if (base + lane < end) {
                bidx = csr_src[base + lane];
                bal = __expf(leaky02(es[bidx] + edd) - m) * inv;
                bnw = dis[bidx] * disd;
            }
        }
        int j = 0;
        for (; j + 4 <= cnt; j += 4) {
            int   s0 = __shfl(bidx, j),     s1 = __shfl(bidx, j + 1);
            int   s2 = __shfl(bidx, j + 2), s3 = __shfl(bidx, j + 3);
            float a0 = __shfl(bal, j),      a1 = __shfl(bal, j + 1);
            float a2 = __shfl(bal, j + 2),  a3 = __shfl(bal, j + 3);
            float n0 = __shfl(bnw, j),      n1 = __shfl(bnw, j + 1);
            float n2 = __shfl(bnw, j + 2),  n3 = __shfl(bnw, j + 3);
            uint w0 = *(const uint*)(xb + (size_t)s0 * 128 + lane * 2);
            uint w1 = *(const uint*)(xb + (size_t)s1 * 128 + lane * 2);
            uint w2 = *(const uint*)(xb + (size_t)s2 * 128 + lane * 2);
            uint w3 = *(const uint*)(xb + (size_t)s3 * 128 + lane * 2);
            float p0, p1;
            p0 = b2f_lo(w0); p1 = b2f_hi(w0);
            gat0 += a0 * p0; gat1 += a0 * p1; gin0 += p0; gin1 += p1; gcn0 += n0 * p0; gcn1 += n0 * p1;
            p0 = b2f_lo(w1); p1 = b2f_hi(w1);
            gat0 += a1 * p0; gat1 += a1 * p1; gin0 += p0; gin1 += p1; gcn0 += n1 * p0; gcn1 += n1 * p1;
            p0 = b2f_lo(w2); p1 = b2f_hi(w2);
            gat0 += a2 * p0; gat1 += a2 * p1; gin0 += p0; gin1 += p1; gcn0 += n2 * p0; gcn1 += n2 * p1;
            p0 = b2f_lo(w3); p1 = b2f_hi(w3);
            gat0 += a3 * p0; gat1 += a3 * p1; gin0 += p0; gin1 += p1; gcn0 += n3 * p0; gcn1 += n3 * p1;
        }
        for (; j < cnt; ++j) {
            int   s0 = __shfl(bidx, j);
            float a0 = __shfl(bal, j);
            float n0 = __shfl(bnw, j);
            uint w0 = *(const uint*)(xb + (size_t)s0 * 128 + lane * 2);
            float p0 = b2f_lo(w0), p1 = b2f_hi(w0);
            gat0 += a0 * p0; gat1 += a0 * p1; gin0 += p0; gin1 += p1; gcn0 += n0 * p0; gcn1 += n0 * p1;
        }
    }
    ushort* orow = aggb + (size_t)d * 384;
    *(uint*)(orow + lane * 2)       = pack2(gat0, gat1);
    *(uint*)(orow + 128 + lane * 2) = pack2(gin0, gin1);
    *(uint*)(orow + 256 + lane * 2) = pack2(gcn0, gcn1);
}

// ---------------- pipelined bf16 MFMA GEMM core, BM=256 tile: counted vmcnt, 2 buffers, 2 raw barriers ----
// Tile 256 rows x 128 cols; per stage 6 gload_lds (4 A-units of 64 rows + 2 B-units). LDS buffer =
// 12288 ushorts (A 8192 | B 4096), x2 double-buffer. BN partials: deterministic exactly-one-writer
// via sred (fixed order half0+half1). DIRECT C epilogue (LDS-staged version regressed r8/r9).
__device__ __forceinline__ void gemm_core(
    const ushort* __restrict__ A, int lda, const ushort* __restrict__ Bt,
    const float* __restrict__ bias, float* __restrict__ pstat, int colbase,
    ushort* __restrict__ Cb, int ldc, int M, int K, int relu,
    ushort* lds, float* sred)
{
    const int tid = threadIdx.x;
    const int wave = tid >> 6, lane = tid & 63;
    const int row0 = blockIdx.x * 256;
    const int col0 = blockIdx.y * 128;

    int ar0 = min(row0 +   0 + wave * 16 + (lane >> 2), M - 1);
    int ar1 = min(row0 +  64 + wave * 16 + (lane >> 2), M - 1);
    int ar2 = min(row0 + 128 + wave * 16 + (lane >> 2), M - 1);
    int ar3 = min(row0 + 192 + wave * 16 + (lane >> 2), M - 1);
    int br0 = col0 + wave * 16 + (lane >> 2);
    int br1 = col0 + 64 + wave * 16 + (lane >> 2);
    const ushort* pa0 = A + (size_t)ar0 * lda + (lane & 3) * 8;
    const ushort* pa1 = A + (size_t)ar1 * lda + (lane & 3) * 8;
    const ushort* pa2 = A + (size_t)ar2 * lda + (lane & 3) * 8;
    const ushort* pa3 = A + (size_t)ar3 * lda + (lane & 3) * 8;
    const ushort* pb0 = Bt + (size_t)br0 * K + (lane & 3) * 8;
    const ushort* pb1 = Bt + (size_t)br1 * K + (lane & 3) * 8;
    const int wr = (wave >> 1) * 128, wc = (wave & 1) * 64;

    f32x4 zero = {0.f, 0.f, 0.f, 0.f};
    f32x4 acc[8][4];
    #pragma unroll
    for (int m = 0; m < 8; ++m)
        #pragma unroll
        for (int n = 0; n < 4; ++n) acc[m][n] = zero;

    const int nt = K >> 5;

#define STAGE_C(bufi) { \
    ushort* Lb = lds + (bufi) * 12288; \
    __builtin_amdgcn_global_load_lds((const __attribute__((address_space(1))) void*)pa0, \
        (__attribute__((address_space(3))) void*)(Lb + wave * 512), 16, 0, 0); \
    __builtin_amdgcn_global_load_lds((const __attribute__((address_space(1))) void*)pa1, \
        (__attribute__((address_space(3))) void*)(Lb + 2048 + wave * 512), 16, 0, 0); \
    __builtin_amdgcn_global_load_lds((const __attribute__((address_space(1))) void*)pa2, \
        (__attribute__((address_space(3))) void*)(Lb + 4096 + wave * 512), 16, 0, 0); \
    __builtin_amdgcn_global_load_lds((const __attribute__((address_space(1))) void*)pa3, \
        (__attribute__((address_space(3))) void*)(Lb + 6144 + wave * 512), 16, 0, 0); \
    __builtin_amdgcn_global_load_lds((const __attribute__((address_space(1))) void*)pb0, \
        (__attribute__((address_space(3))) void*)(Lb + 8192 + wave * 512), 16, 0, 0); \
    __builtin_amdgcn_global_load_lds((const __attribute__((address_space(1))) void*)pb1, \
        (__attribute__((address_space(3))) void*)(Lb + 10240 + wave * 512), 16, 0, 0); \
    pa0 += 32; pa1 += 32; pa2 += 32; pa3 += 32; pb0 += 32; pb1 += 32; }

    STAGE_C(0);
    for (int t = 0; t < nt; ++t) {
        int cur = t & 1;
        if (t + 1 < nt) {
            STAGE_C(cur ^ 1);
            asm volatile("s_waitcnt vmcnt(6) lgkmcnt(0)" ::: "memory");
        } else {
            asm volatile("s_waitcnt vmcnt(0) lgkmcnt(0)" ::: "memory");
        }
        __builtin_amdgcn_s_barrier();
        const ushort* As = lds + cur * 12288;
        const ushort* Bs = As + 8192;
        short8 a[8], b[4];
        #pragma unroll
        for (int m = 0; m < 8; ++m)
            a[m] = *(const short8*)&As[(wr + m * 16 + (lane & 15)) * 32 + (lane >> 4) * 8];
        #pragma unroll
        for (int n = 0; n < 4; ++n)
            b[n] = *(const short8*)&Bs[(wc + n * 16 + (lane & 15)) * 32 + (lane >> 4) * 8];
        #pragma unroll
        for (int m = 0; m < 8; ++m)
            #pragma unroll
            for (int n = 0; n < 4; ++n)
                acc[m][n] = __builtin_amdgcn_mfma_f32_16x16x32_bf16(a[m], b[n], acc[m][n], 0, 0, 0);
        if (t + 1 < nt) __builtin_amdgcn_s_barrier();
    }
#undef STAGE_C

    // direct epilogue: C/D layout col=lane&15, row=(lane>>4)*4+reg
    #pragma unroll
    for (int n = 0; n < 4; ++n) {
        int col = col0 + wc + n * 16 + (lane & 15);
        float bb = bias ? bias[col] : 0.f;
        float s_acc = 0.f, q_acc = 0.f;
        #pragma unroll
        for (int m = 0; m < 8; ++m) {
            int rb = row0 + wr + m * 16 + (lane >> 4) * 4;
            #pragma unroll
            for (int r = 0; r < 4; ++r) {
                int row = rb + r;
                if (row < M) {
                    float v = acc[m][n][r] + bb;
                    if (relu) v = fmaxf(v, 0.f);
                    Cb[(size_t)row * ldc + col] = f2b(v);
                    s_acc += v; q_acc += v * v;
                }
            }
        }
        if (pstat) {
            s_acc += __shfl_xor(s_acc, 16); q_acc += __shfl_xor(q_acc, 16);
            s_acc += __shfl_xor(s_acc, 32); q_acc += __shfl_xor(q_acc, 32);
            if (lane < 16) {
                int cl = wc + n * 16 + (lane & 15);   // 0..127 within block
                int half = wave >> 1;                 // row-half 0/1 (128 rows each)
                sred[half * 128 + cl] = s_acc;
                sred[256 + half * 128 + cl] = q_acc;
            }
        }
    }
    if (pstat) {
        __syncthreads();
        int c = tid & 127, which = tid >> 7;          // which: 0=sum, 1=sumsq
        float v = sred[which * 256 + c] + sred[which * 256 + 128 + c];   // fixed order: half0+half1
        size_t gcol = (size_t)(colbase + col0 + c);
        pstat[(which ? (size_t)NRB * 768 : 0) + (size_t)blockIdx.x * 768 + gcol] = v;
    }
}

// ---------------- z-batched branch GEMMs: z=0 GAT, z=1 GIN1, z=2 GCN (all K=128, lda=384) ----------------
__global__ __launch_bounds__(256) void mm_gemm3(
    const ushort* __restrict__ aggb,
    const ushort* __restrict__ wt_gat, const ushort* __restrict__ wt_gin1, const ushort* __restrict__ wt_gcn,
    const float* __restrict__ b_gat, const float* __restrict__ b_gin1, const float* __restrict__ b_gcn,
    float* __restrict__ pstat,
    ushort* __restrict__ xcb, ushort* __restrict__ hid_b)
{
    __shared__ ushort lds[24576];
    __shared__ float sred[512];
    if (blockIdx.z == 0)
        gemm_core(aggb,       384, wt_gat,  b_gat,  pstat,   0,   xcb,       768, NN, 128, 0, lds, sred);
    else if (blockIdx.z == 1)
        gemm_core(aggb + 128, 384, wt_gin1, b_gin1, nullptr, 0,   hid_b,     256, NN, 128, 1, lds, sred);
    else
        gemm_core(aggb + 256, 384, wt_gcn,  b_gcn,  pstat,   512, xcb + 512, 768, NN, 128, 0, lds, sred);
}

// ---------------- generic pipelined GEMM (gin2: K=256) ----------------
__global__ __launch_bounds__(256) void mm_gemm_bf(
    const ushort* __restrict__ A, int lda, const ushort* __restrict__ Bt,
    const float* __restrict__ bias, float* __restrict__ pstat, int colbase,
    ushort* __restrict__ Cb, int ldc, int M, int K, int relu)
{
    __shared__ ushort lds[24576];
    __shared__ float sred[512];
    gemm_core(A, lda, Bt, bias, pstat, colbase, Cb, ldc, M, K, relu, lds, sred);
}

// ---------------- BN+ReLU transform (sc/sh from LDS) ----------------
__device__ __forceinline__ uint4 bn_relu_pack_l(uint4 w, const float* sc, const float* sh, int c)
{
    uint4 o;
    o.x = pack2(fmaxf(b2f_lo(w.x) * sc[c + 0] + sh[c + 0], 0.f), fmaxf(b2f_hi(w.x) * sc[c + 1] + sh[c + 1], 0.f));
    o.y = pack2(fmaxf(b2f_lo(w.y) * sc[c + 2] + sh[c + 2], 0.f), fmaxf(b2f_hi(w.y) * sc[c + 3] + sh[c + 3], 0.f));
    o.z = pack2(fmaxf(b2f_lo(w.z) * sc[c + 4] + sh[c + 4], 0.f), fmaxf(b2f_hi(w.z) * sc[c + 5] + sh[c + 5], 0.f));
    o.w = pack2(fmaxf(b2f_lo(w.w) * sc[c + 6] + sh[c + 6], 0.f), fmaxf(b2f_hi(w.w) * sc[c + 7] + sh[c + 7], 0.f));
    return o;
}

// ---------------- head GEMM, BM=256, pipelined: BN+ReLU fused A reg-staging, B via global_load_lds -------
__global__ __launch_bounds__(256) void mm_gemm_bn(
    const ushort* __restrict__ A, const ushort* __restrict__ Bt,
    const float* __restrict__ bias,
    const float* __restrict__ sc, const float* __restrict__ sh,
    ushort* __restrict__ Cb, int ldc, int M)
{
    const int K = 768, lda = 768;
    __shared__ ushort lds[24576];
    __shared__ float sc_l[768], sh_l[768];
    const int tid = threadIdx.x;
    for (int i = tid; i < 768; i += 256) { sc_l[i] = sc[i]; sh_l[i] = sh[i]; }

    const int wave = tid >> 6, lane = tid & 63;
    const int row0 = blockIdx.x * 256;
    const int col0 = blockIdx.y * 128;

    int ar0 = min(row0 +   0 + wave * 16 + (lane >> 2), M - 1);
    int ar1 = min(row0 +  64 + wave * 16 + (lane >> 2), M - 1);
    int ar2 = min(row0 + 128 + wave * 16 + (lane >> 2), M - 1);
    int ar3 = min(row0 + 192 + wave * 16 + (lane >> 2), M - 1);
    int br0 = col0 + wave * 16 + (lane >> 2);
    int br1 = col0 + 64 + wave * 16 + (lane >> 2);
    const ushort* pa0 = A + (size_t)ar0 * lda + (lane & 3) * 8;
    const ushort* pa1 = A + (size_t)ar1 * lda + (lane & 3) * 8;
    const ushort* pa2 = A + (size_t)ar2 * lda + (lane & 3) * 8;
    const ushort* pa3 = A + (size_t)ar3 * lda + (lane & 3) * 8;
    const ushort* pb0 = Bt + (size_t)br0 * K + (lane & 3) * 8;
    const ushort* pb1 = Bt + (size_t)br1 * K + (lane & 3) * 8;
    const int wr = (wave >> 1) * 128, wc = (wave & 1) * 64;

    f32x4 zero = {0.f, 0.f, 0.f, 0.f};
    f32x4 acc[8][4];
    #pragma unroll
    for (int m = 0; m < 8; ++m)
        #pragma unroll
        for (int n = 0; n < 4; ++n) acc[m][n] = zero;

    const int nt = K >> 5;   // 24

#define STAGE_B(bufi) { \
    ushort* Lb = lds + (bufi) * 12288; \
    __builtin_amdgcn_global_load_lds((const __attribute__((address_space(1))) void*)pb0, \
        (__attribute__((address_space(3))) void*)(Lb + 8192 + wave * 512), 16, 0, 0); \
    __builtin_amdgcn_global_load_lds((const __attribute__((address_space(1))) void*)pb1, \
        (__attribute__((address_space(3))) void*)(Lb + 10240 + wave * 512), 16, 0, 0); \
    pb0 += 32; pb1 += 32; }

    // prologue: tile 0 (full drain once; also covers sc_l/sh_l staging)
    uint4 w0 = *(const uint4*)pa0, w1 = *(const uint4*)pa1;
    uint4 w2 = *(const uint4*)pa2, w3 = *(const uint4*)pa3;
    pa0 += 32; pa1 += 32; pa2 += 32; pa3 += 32;
    STAGE_B(0);
    __syncthreads();
    {
        int c = (lane & 3) * 8;
        *(uint4*)(lds + wave * 512 + lane * 8)        = bn_relu_pack_l(w0, sc_l, sh_l, c);
        *(uint4*)(lds + 2048 + wave * 512 + lane * 8) = bn_relu_pack_l(w1, sc_l, sh_l, c);
        *(uint4*)(lds + 4096 + wave * 512 + lane * 8) = bn_relu_pack_l(w2, sc_l, sh_l, c);
        *(uint4*)(lds + 6144 + wave * 512 + lane * 8) = bn_relu_pack_l(w3, sc_l, sh_l, c);
    }

    for (int t = 0; t < nt; ++t) {
        int cur = t & 1;
        bool more = (t + 1 < nt);
        uint4 w0n, w1n, w2n, w3n;
        if (more) {
            w0n = *(const uint4*)pa0; w1n = *(const uint4*)pa1;   // A-reg loads FIRST (oldest)
            w2n = *(const uint4*)pa2; w3n = *(const uint4*)pa3;
            pa0 += 32; pa1 += 32; pa2 += 32; pa3 += 32;
            STAGE_B(cur ^ 1);
            asm volatile("s_waitcnt vmcnt(6) lgkmcnt(0)" ::: "memory");
        } else {
            asm volatile("s_waitcnt vmcnt(0) lgkmcnt(0)" ::: "memory");
        }
        __builtin_amdgcn_s_barrier();
        const ushort* As = lds + cur * 12288;
        const ushort* Bs = As + 8192;
        short8 a[8], b[4];
        #pragma unroll
        for (int m = 0; m < 8; ++m)
            a[m] = *(const short8*)&As[(wr + m * 16 + (lane & 15)) * 32 + (lane >> 4) * 8];
        #pragma unroll
        for (int n = 0; n < 4; ++n)
            b[n] = *(const short8*)&Bs[(wc + n * 16 + (lane & 15)) * 32 + (lane >> 4) * 8];
        #pragma unroll
        for (int m = 0; m < 8; ++m)
            #pragma unroll
            for (int n = 0; n < 4; ++n)
                acc[m][n] = __builtin_amdgcn_mfma_f32_16x16x32_bf16(a[m], b[n], acc[m][n], 0, 0, 0);
        if (more) {
            int c = (t + 1) * 32 + (lane & 3) * 8;
            ushort* Ln = lds + (cur ^ 1) * 12288;
            *(uint4*)(Ln + wave * 512 + lane * 8)        = bn_relu_pack_l(w0n, sc_l, sh_l, c);
            *(uint4*)(Ln + 2048 + wave * 512 + lane * 8) = bn_relu_pack_l(w1n, sc_l, sh_l, c);
            *(uint4*)(Ln + 4096 + wave * 512 + lane * 8) = bn_relu_pack_l(w2n, sc_l, sh_l, c);
            *(uint4*)(Ln + 6144 + wave * 512 + lane * 8) = bn_relu_pack_l(w3n, sc_l, sh_l, c);
            __builtin_amdgcn_s_barrier();
        }
    }
#undef STAGE_B

    #pragma unroll
    for (int n = 0; n < 4; ++n) {
        int col = col0 + wc + n * 16 + (lane & 15);
        float bb = bias[col];
        #pragma unroll
        for (int m = 0; m < 8; ++m) {
            int rb = row0 + wr + m * 16 + (lane >> 4) * 4;
            #pragma unroll
            for (int r = 0; r < 4; ++r) {
                int row = rb + r;
                if (row < M)
                    Cb[(size_t)row * ldc + col] = f2b(fmaxf(acc[m][n][r] + bb, 0.f));
            }
        }
    }
}

// reduce per-rowblock partials in fixed serial order -> deterministic BN scale/shift
__global__ void mm_bn_fin(const float* __restrict__ pstat, const float* __restrict__ gamma,
                          const float* __restrict__ beta,
                          float* __restrict__ scale, float* __restrict__ shift)
{
    int c = blockIdx.x * 256 + threadIdx.x;
    if (c >= 768) return;
    const float* ps = pstat + c;
    const float* pq = pstat + (size_t)NRB * 768 + c;
    float s = 0.f, q = 0.f;
    for (int rb = 0; rb < NRB; ++rb) {
        s += ps[(size_t)rb * 768];
        q += pq[(size_t)rb * 768];
    }
    float invn = 1.f / (float)NN;
    float mu = s * invn;
    float ex2 = q * invn;
    float var = fmaxf(ex2 - mu * mu, 0.f);
    float rs = rsqrtf(var + 1e-5f);
    float sc = gamma[c] * rs;
    scale[c] = sc;
    shift[c] = beta[c] - mu * sc;
}

// ---------------- out = h2 @ W2 + b2 (h2 bf16 [NN,256], W2 fp32 [256,40]) ----------------
__global__ __launch_bounds__(256) void mm_head2(const ushort* __restrict__ h2b, const float* __restrict__ W2,
                                                const float* __restrict__ b2, float* __restrict__ out)
{
    __shared__ float Ws[256 * 40];
    for (int i = threadIdx.x; i < 256 * 40; i += 256) Ws[i] = W2[i];
    __syncthreads();
    int row = blockIdx.x * 32 + (threadIdx.x >> 3);
    int cg = (threadIdx.x & 7) * 5;
    if (row >= NN) return;
    const ushort* hr = h2b + (size_t)row * 256;
    float acc[5] = {0, 0, 0, 0, 0};
    for (int k = 0; k < 256; k += 8) {
        uint4 w = *(const uint4*)(hr + k);
        float a0 = b2f_lo(w.x), a1 = b2f_hi(w.x), a2 = b2f_lo(w.y), a3 = b2f_hi(w.y);
        float a4 = b2f_lo(w.z), a5 = b2f_hi(w.z), a6 = b2f_lo(w.w), a7 = b2f_hi(w.w);
        #pragma unroll
        for (int j = 0; j < 5; ++j) {
            acc[j] += a0 * Ws[(k + 0) * 40 + cg + j] + a1 * Ws[(k + 1) * 40 + cg + j]
                    + a2 * Ws[(k + 2) * 40 + cg + j] + a3 * Ws[(k + 3) * 40 + cg + j]
                    + a4 * Ws[(k + 4) * 40 + cg + j] + a5 * Ws[(k + 5) * 40 + cg + j]
                    + a6 * Ws[(k + 6) * 40 + cg + j] + a7 * Ws[(k + 7) * 40 + cg + j];
        }
    }
    #pragma unroll
    for (int j = 0; j < 5; ++j) out[(size_t)row * 40 + cg + j] = acc[j] + b2[cg + j];
}

extern "C" void kernel_launch(void* const* d_in, const int* in_sizes, int n_in,
                              void* d_out, int out_size, void* d_ws, size_t ws_size,
                              hipStream_t stream)
{
    const float* x      = (const float*)d_in[0];
    const int*   ei     = (const int*)d_in[1];
    const float* W_gat  = (const float*)d_in[2];
    const float* att_s  = (const float*)d_in[3];
    const float* att_d  = (const float*)d_in[4];
    const float* b_gat  = (const float*)d_in[5];
    const float* W_gin1 = (const float*)d_in[6];
    const float* b_gin1 = (const float*)d_in[7];
    const float* W_gin2 = (const float*)d_in[8];
    const float* b_gin2 = (const float*)d_in[9];
    const float* W_gcn  = (const float*)d_in[10];
    const float* b_gcn  = (const float*)d_in[11];
    const float* gamma  = (const float*)d_in[12];
    const float* beta   = (const float*)d_in[13];
    const float* W_lin  = (const float*)d_in[14];
    const float* b_lin  = (const float*)d_in[15];
    const float* W_lin2 = (const float*)d_in[16];
    const float* b_lin2 = (const float*)d_in[17];
    const int* src = ei;
    const int* dst = ei + NE;
    float* out = (float*)d_out;

    float* ws = (float*)d_ws;
    size_t off = 0;
    ushort* xb      = (ushort*)(ws + off); off += (size_t)NN * 64;    // [NN][128] bf16
    ushort* aggb    = (ushort*)(ws + off); off += (size_t)NN * 192;   // [NN][384] bf16: gat|gin|gcn
    ushort* hid_b   = (ushort*)(ws + off); off += (size_t)NN * 128;   // GIN hidden; later h2
    ushort* xcb     = (ushort*)(ws + off); off += (size_t)NN * 384;   // [NN][768] bf16
    float* es       = ws + off; off += NN;
    float* ed       = ws + off; off += NN;
    float* dis      = ws + off; off += NN;
    float* va       = ws + off; off += 128;
    float* vd       = ws + off; off += 128;
    float* pstat    = ws + off; off += (size_t)1536 * NRB;   // BN partials: [NRB][768] sum | [NRB][768] sumsq
    float* bscale   = ws + off; off += 768;
    float* bshift   = ws + off; off += 768;
    ushort* wt_gat  = (ushort*)(ws + off); off += 128 * 256 / 2;
    ushort* wt_gin1 = (ushort*)(ws + off); off += 128 * 256 / 2;
    ushort* wt_gin2 = (ushort*)(ws + off); off += 256 * 256 / 2;
    ushort* wt_gcn  = (ushort*)(ws + off); off += 128 * 256 / 2;
    ushort* wt_lin  = (ushort*)(ws + off); off += 768 * 256 / 2;
    int* part       = (int*)(ws + off); off += 256;
    int* row_ptr    = (int*)(ws + off); off += NN + 1;
    int* cursor     = (int*)(ws + off); off += NN;
    int* csr_src    = (int*)(ws + off); off += NE;

    dim3 blk(256);
    dim3 gemm_grid(NRB, 2);       // BM=256 -> 196 row blocks, 2 col blocks
    dim3 gemm_grid3(NRB, 2, 3);   // 3 branch GEMMs batched
    const int NB = (NN + 255) / 256;           // scan tiles

    // ---- zero cursor early (pstat needs no memset: every slot written exactly once) ----
    hipMemsetAsync(cursor, 0, NN * sizeof(int), stream);

    // ---- weight transposes (one launch) / attention vectors ----
    mm_wt_all<<<(360448 + 255) / 256, blk, 0, stream>>>(W_gat, W_gin1, W_gin2, W_gcn, W_lin,
                                                        wt_gat, wt_gin1, wt_gin2, wt_gcn, wt_lin);
    mm_attvec<<<1, blk, 0, stream>>>(W_gat, att_s, att_d, va, vd);

    // ---- fused convert + attention dots ----
    mm_cvt_es<<<(NN + 3) / 4, blk, 0, stream>>>(x, va, vd, xb, es, ed);

    // ---- CSR build ----
    mm_count<<<(NE + 255) / 256, blk, 0, stream>>>(dst, cursor);
    mm_scan1<<<NB, blk, 0, stream>>>(cursor, part);
    mm_scan2<<<1, blk, 0, stream>>>(part, NB);
    mm_scan3<<<NB, blk, 0, stream>>>(cursor, part, row_ptr, cursor);
    mm_dis<<<(NN + 255) / 256, blk, 0, stream>>>(row_ptr, dis);
    mm_fill<<<(NE + 255) / 256, blk, 0, stream>>>(src, dst, cursor, csr_src);

    // ---- fused per-node sort + softmax + 3-way gather ----
    mm_node_agg<<<(NN + 3) / 4, blk, 0, stream>>>(row_ptr, csr_src, es, ed, dis, xb, aggb);

    // ---- branch GEMMs (z-batched; BN partials fused, no atomics) ----
    mm_gemm3<<<gemm_grid3, blk, 0, stream>>>(aggb, wt_gat, wt_gin1, wt_gcn,
                                             b_gat, b_gin1, b_gcn, pstat, xcb, hid_b);
    // ---- gin2 (depends on gin1 output) ----
    mm_gemm_bf<<<gemm_grid, blk, 0, stream>>>(hid_b, 256, wt_gin2, b_gin2, pstat, 256,
                                              xcb + 256, 768, NN, 256, 0);

    // ---- BN scale/shift (deterministic serial reduce) ----
    mm_bn_fin<<<3, blk, 0, stream>>>(pstat, gamma, beta, bscale, bshift);

    // ---- head: BN+ReLU fused into A staging (pipelined, BM=256) ----
    mm_gemm_bn<<<gemm_grid, blk, 0, stream>>>(xcb, wt_lin, b_lin, bscale, bshift, hid_b, 256, NN);
    mm_head2<<<(NN + 31) / 32, blk, 0, stream>>>(hid_b, W_lin2, b_lin2, out);
}

// Round 14
// 381.493 us; speedup vs baseline: 1.0868x; 1.0868x over previous
//
#include <hip/hip_runtime.h>
#include <math.h>

#define NN 50000
#define NE 500000
#define NRB 391   // (NN+127)/128 row blocks per GEMM (BM=128; BM=256 regressed r13: occupancy cliff)
// D_IN=128, D_H=256, D_C=768, D_OUT=40

typedef __attribute__((ext_vector_type(8))) short short8;   // 8 bf16 (4 VGPRs)
typedef __attribute__((ext_vector_type(4))) float f32x4;    // MFMA acc

__device__ __forceinline__ float leaky02(float x) { return x > 0.f ? x : 0.2f * x; }
__device__ __forceinline__ ushort f2b(float f) {
    uint u = __float_as_uint(f);
    u += 0x7fffu + ((u >> 16) & 1u);          // RNE
    return (ushort)(u >> 16);
}
__device__ __forceinline__ float b2f(ushort h) { return __uint_as_float(((uint)h) << 16); }
__device__ __forceinline__ float b2f_lo(uint w) { return __uint_as_float(w << 16); }
__device__ __forceinline__ float b2f_hi(uint w) { return __uint_as_float(w & 0xffff0000u); }
__device__ __forceinline__ uint pack2(float a, float b) {
    return (uint)f2b(a) | ((uint)f2b(b) << 16);
}

// ---------------- all weight transposes in one launch: W [K][256] fp32 -> Wt [256][K] bf16 ----------------
__global__ void mm_wt_all(const float* __restrict__ Wg, const float* __restrict__ Wi1,
                          const float* __restrict__ Wi2, const float* __restrict__ Wc,
                          const float* __restrict__ Wl,
                          ushort* __restrict__ tg, ushort* __restrict__ ti1,
                          ushort* __restrict__ ti2, ushort* __restrict__ tc,
                          ushort* __restrict__ tl)
{
    int idx = blockIdx.x * 256 + threadIdx.x;
    const float* W; ushort* T; int K; int base;
    if (idx < 32768)       { W = Wg;  T = tg;  K = 128; base = 0; }
    else if (idx < 65536)  { W = Wi1; T = ti1; K = 128; base = 32768; }
    else if (idx < 131072) { W = Wi2; T = ti2; K = 256; base = 65536; }
    else if (idx < 163840) { W = Wc;  T = tc;  K = 128; base = 131072; }
    else if (idx < 360448) { W = Wl;  T = tl;  K = 768; base = 163840; }
    else return;
    int i = idx - base;
    int n = i / K, k = i - n * K;
    T[i] = f2b(W[(size_t)k * 256 + n]);
}

// ---------------- va = W_gat @ att_src, vd = W_gat @ att_dst (both [128]) ----------------
__global__ void mm_attvec(const float* __restrict__ W, const float* __restrict__ as_,
                          const float* __restrict__ ad_, float* __restrict__ va, float* __restrict__ vd)
{
    int i = threadIdx.x;           // 0..255
    const float* vec = (i < 128) ? as_ : ad_;
    int k = i & 127;
    float s = 0.f;
    for (int j = 0; j < 256; ++j) s += W[(size_t)k * 256 + j] * vec[j];
    if (i < 128) va[k] = s; else vd[k] = s;
}

// ---------------- fused: x fp32 -> xb bf16, es/ed = x.va / x.vd (wave per node) ----------------
__global__ __launch_bounds__(256) void mm_cvt_es(const float* __restrict__ x,
                                                 const float* __restrict__ va, const float* __restrict__ vd,
                                                 ushort* __restrict__ xb,
                                                 float* __restrict__ es, float* __restrict__ ed)
{
    int node = blockIdx.x * 4 + (threadIdx.x >> 6);
    int lane = threadIdx.x & 63;
    if (node >= NN) return;
    float2 xv = *(const float2*)(x + (size_t)node * 128 + lane * 2);
    float2 a = *(const float2*)(va + lane * 2);
    float2 b = *(const float2*)(vd + lane * 2);
    *(uint*)(xb + (size_t)node * 128 + lane * 2) = pack2(xv.x, xv.y);
    float s = xv.x * a.x + xv.y * a.y;
    float d = xv.x * b.x + xv.y * b.y;
    #pragma unroll
    for (int off = 32; off; off >>= 1) {
        s += __shfl_down(s, off);
        d += __shfl_down(d, off);
    }
    if (lane == 0) { es[node] = s; ed[node] = d; }
}

// ---------------- CSR build: count -> 3-phase scan -> fill ----------------
__global__ void mm_count(const int* __restrict__ dst, int* __restrict__ deg)
{
    int e = blockIdx.x * 256 + threadIdx.x;
    if (e >= NE) return;
    atomicAdd(&deg[dst[e]], 1);
}

__global__ __launch_bounds__(256) void mm_scan1(const int* __restrict__ deg, int* __restrict__ part)
{
    __shared__ int red[256];
    int i = blockIdx.x * 256 + threadIdx.x;
    red[threadIdx.x] = (i < NN) ? deg[i] : 0;
    __syncthreads();
    for (int off = 128; off; off >>= 1) {
        if (threadIdx.x < off) red[threadIdx.x] += red[threadIdx.x + off];
        __syncthreads();
    }
    if (threadIdx.x == 0) part[blockIdx.x] = red[0];
}

__global__ __launch_bounds__(256) void mm_scan2(int* __restrict__ part, int nb)
{
    __shared__ int tile[256];
    int t = threadIdx.x;
    int v = (t < nb) ? part[t] : 0;
    tile[t] = v; __syncthreads();
    for (int off = 1; off < 256; off <<= 1) {
        int a = (t >= off) ? tile[t - off] : 0;
        __syncthreads();
        tile[t] += a;
        __syncthreads();
    }
    if (t < nb) part[t] = tile[t] - v;   // exclusive
}

__global__ __launch_bounds__(256) void mm_scan3(const int* __restrict__ deg, const int* __restrict__ part,
                                                int* __restrict__ row_ptr, int* __restrict__ cursor)
{
    __shared__ int tile[256];
    int t = threadIdx.x;
    int i = blockIdx.x * 256 + t;
    int v = (i < NN) ? deg[i] : 0;
    tile[t] = v; __syncthreads();
    for (int off = 1; off < 256; off <<= 1) {
        int a = (t >= off) ? tile[t - off] : 0;
        __syncthreads();
        tile[t] += a;
        __syncthreads();
    }
    if (i < NN) {
        int ex = part[blockIdx.x] + tile[t] - v;
        row_ptr[i] = ex;
        cursor[i] = ex;
    }
    if (i == 0) row_ptr[NN] = NE;
}

__global__ void mm_fill(const int* __restrict__ src, const int* __restrict__ dst,
                        int* __restrict__ cursor, int* __restrict__ csr_src)
{
    int e = blockIdx.x * 256 + threadIdx.x;
    if (e >= NE) return;
    int pos = atomicAdd(&cursor[dst[e]], 1);
    csr_src[pos] = src[e];
}

__global__ void mm_dis(const int* __restrict__ row_ptr, float* __restrict__ dis)
{
    int i = blockIdx.x * 256 + threadIdx.x;
    if (i >= NN) return;
    dis[i] = rsqrtf((float)(row_ptr[i + 1] - row_ptr[i] + 1));
}

// ---------------- fused per-node: in-reg segment sort (determinism) + GAT softmax + 3-way gather ----------------
__global__ __launch_bounds__(256) void mm_node_agg(
    const int* __restrict__ row_ptr, const int* __restrict__ csr_src,
    const float* __restrict__ es, const float* __restrict__ ed,
    const float* __restrict__ dis,
    const ushort* __restrict__ xb, ushort* __restrict__ aggb)
{
    int d = blockIdx.x * 4 + (threadIdx.x >> 6);
    int lane = threadIdx.x & 63;
    if (d >= NN) return;
    int start = row_ptr[d], end = row_ptr[d + 1];
    int deg = end - start;
    float edd = ed[d], disd = dis[d];
    float selfv = leaky02(es[d] + edd);

    int myidx = (start + lane < end) ? csr_src[start + lane] : 0x7fffffff;
    if (deg <= 64) {
        #pragma unroll
        for (int k = 2; k <= 64; k <<= 1) {
            #pragma unroll
            for (int j = k >> 1; j > 0; j >>= 1) {
                int o = __shfl_xor(myidx, j);
                bool keepmin = (((lane & k) == 0) == ((lane & j) == 0));
                myidx = keepmin ? min(myidx, o) : max(myidx, o);
            }
        }
    }
    bool valid = (lane < deg);
    float myl = -3.0e38f, mynw = 0.f;
    if (valid) {
        myl = leaky02(es[myidx] + edd);
        mynw = dis[myidx] * disd;
    }
    float lmax = fmaxf(selfv, myl);
    for (int e = start + 64 + lane; e < end; e += 64)
        lmax = fmaxf(lmax, leaky02(es[csr_src[e]] + edd));
    #pragma unroll
    for (int off = 1; off < 64; off <<= 1) lmax = fmaxf(lmax, __shfl_xor(lmax, off));
    float m = lmax;

    float lsum = valid ? __expf(myl - m) : 0.f;
    if (lane == 0) lsum += __expf(selfv - m);
    for (int e = start + 64 + lane; e < end; e += 64)
        lsum += __expf(leaky02(es[csr_src[e]] + edd) - m);
    #pragma unroll
    for (int off = 1; off < 64; off <<= 1) lsum += __shfl_xor(lsum, off);
    float inv = 1.f / lsum;
    float myal = __expf(myl - m) * inv;

    float aself = __expf(selfv - m) * inv;
    float d2 = disd * disd;
    uint wself = *(const uint*)(xb + (size_t)d * 128 + lane * 2);
    float x0 = b2f_lo(wself), x1 = b2f_hi(wself);
    float gat0 = aself * x0, gat1 = aself * x1;
    float gin0 = x0, gin1 = x1;
    float gcn0 = d2 * x0, gcn1 = d2 * x1;

    for (int base = start; base < end; base += 64) {
        int cnt = min(64, end - base);
        int bidx; float bal, bnw;
        if (base == start) { bidx = myidx; bal = myal; bnw = mynw; }
        else {
            bidx = -1; bal = 0.f; bnw = 0.f;
            if (base + lane < end) {
                bidx = csr_src[base + lane];
                bal = __expf(leaky02(es[bidx] + edd) - m) * inv;
                bnw = dis[bidx] * disd;
            }
        }
        int j = 0;
        for (; j + 4 <= cnt; j += 4) {
            int   s0 = __shfl(bidx, j),     s1 = __shfl(bidx, j + 1);
            int   s2 = __shfl(bidx, j + 2), s3 = __shfl(bidx, j + 3);
            float a0 = __shfl(bal, j),      a1 = __shfl(bal, j + 1);
            float a2 = __shfl(bal, j + 2),  a3 = __shfl(bal, j + 3);
            float n0 = __shfl(bnw, j),      n1 = __shfl(bnw, j + 1);
            float n2 = __shfl(bnw, j + 2),  n3 = __shfl(bnw, j + 3);
            uint w0 = *(const uint*)(xb + (size_t)s0 * 128 + lane * 2);
            uint w1 = *(const uint*)(xb + (size_t)s1 * 128 + lane * 2);
            uint w2 = *(const uint*)(xb + (size_t)s2 * 128 + lane * 2);
            uint w3 = *(const uint*)(xb + (size_t)s3 * 128 + lane * 2);
            float p0, p1;
            p0 = b2f_lo(w0); p1 = b2f_hi(w0);
            gat0 += a0 * p0; gat1 += a0 * p1; gin0 += p0; gin1 += p1; gcn0 += n0 * p0; gcn1 += n0 * p1;
            p0 = b2f_lo(w1); p1 = b2f_hi(w1);
            gat0 += a1 * p0; gat1 += a1 * p1; gin0 += p0; gin1 += p1; gcn0 += n1 * p0; gcn1 += n1 * p1;
            p0 = b2f_lo(w2); p1 = b2f_hi(w2);
            gat0 += a2 * p0; gat1 += a2 * p1; gin0 += p0; gin1 += p1; gcn0 += n2 * p0; gcn1 += n2 * p1;
            p0 = b2f_lo(w3); p1 = b2f_hi(w3);
            gat0 += a3 * p0; gat1 += a3 * p1; gin0 += p0; gin1 += p1; gcn0 += n3 * p0; gcn1 += n3 * p1;
        }
        for (; j < cnt; ++j) {
            int   s0 = __shfl(bidx, j);
            float a0 = __shfl(bal, j);
            float n0 = __shfl(bnw, j);
            uint w0 = *(const uint*)(xb + (size_t)s0 * 128 + lane * 2);
            float p0 = b2f_lo(w0), p1 = b2f_hi(w0);
            gat0 += a0 * p0; gat1 += a0 * p1; gin0 += p0; gin1 += p1; gcn0 += n0 * p0; gcn1 += n0 * p1;
        }
    }
    ushort* orow = aggb + (size_t)d * 384;
    *(uint*)(orow + lane * 2)       = pack2(gat0, gat1);
    *(uint*)(orow + 128 + lane * 2) = pack2(gin0, gin1);
    *(uint*)(orow + 256 + lane * 2) = pack2(gcn0, gcn1);
}

// ---------------- pipelined bf16 MFMA GEMM core (BM=128): counted vmcnt, 2 buffers, 2 raw barriers -------
// BN partials: deterministic exactly-one-writer via sred (fixed-order half0+half1). DIRECT C epilogue
// (LDS-staged version regressed r8/r9 — do not reintroduce without isolated validation).
__device__ __forceinline__ void gemm_core(
    const ushort* __restrict__ A, int lda, const ushort* __restrict__ Bt,
    const float* __restrict__ bias, float* __restrict__ pstat, int colbase,
    ushort* __restrict__ Cb, int ldc, int M, int K, int relu,
    ushort* lds, float* sred)
{
    const int tid = threadIdx.x;
    const int wave = tid >> 6, lane = tid & 63;
    const int row0 = blockIdx.x * 128;
    const int col0 = blockIdx.y * 128;

    int arow0 = min(row0 + wave * 16 + (lane >> 2), M - 1);
    int arow1 = min(row0 + 64 + wave * 16 + (lane >> 2), M - 1);
    int brow0 = col0 + wave * 16 + (lane >> 2);
    int brow1 = col0 + 64 + wave * 16 + (lane >> 2);
    const ushort* pa0 = A + (size_t)arow0 * lda + (lane & 3) * 8;
    const ushort* pa1 = A + (size_t)arow1 * lda + (lane & 3) * 8;
    const ushort* pb0 = Bt + (size_t)brow0 * K + (lane & 3) * 8;
    const ushort* pb1 = Bt + (size_t)brow1 * K + (lane & 3) * 8;
    const int wr = (wave >> 1) * 64, wc = (wave & 1) * 64;

    f32x4 zero = {0.f, 0.f, 0.f, 0.f};
    f32x4 acc[4][4];
    #pragma unroll
    for (int m = 0; m < 4; ++m)
        #pragma unroll
        for (int n = 0; n < 4; ++n) acc[m][n] = zero;

    const int nt = K >> 5;

#define STAGE_C(bufi) { \
    ushort* Lb = lds + (bufi) * 8192; \
    __builtin_amdgcn_global_load_lds((const __attribute__((address_space(1))) void*)pa0, \
        (__attribute__((address_space(3))) void*)(Lb + wave * 512), 16, 0, 0); \
    __builtin_amdgcn_global_load_lds((const __attribute__((address_space(1))) void*)pa1, \
        (__attribute__((address_space(3))) void*)(Lb + 2048 + wave * 512), 16, 0, 0); \
    __builtin_amdgcn_global_load_lds((const __attribute__((address_space(1))) void*)pb0, \
        (__attribute__((address_space(3))) void*)(Lb + 4096 + wave * 512), 16, 0, 0); \
    __builtin_amdgcn_global_load_lds((const __attribute__((address_space(1))) void*)pb1, \
        (__attribute__((address_space(3))) void*)(Lb + 6144 + wave * 512), 16, 0, 0); \
    pa0 += 32; pa1 += 32; pb0 += 32; pb1 += 32; }

    STAGE_C(0);
    for (int t = 0; t < nt; ++t) {
        int cur = t & 1;
        if (t + 1 < nt) {
            STAGE_C(cur ^ 1);
            asm volatile("s_waitcnt vmcnt(4) lgkmcnt(0)" ::: "memory");
        } else {
            asm volatile("s_waitcnt vmcnt(0) lgkmcnt(0)" ::: "memory");
        }
        __builtin_amdgcn_s_barrier();
        const ushort* As = lds + cur * 8192;
        const ushort* Bs = As + 4096;
        short8 a[4], b[4];
        #pragma unroll
        for (int m = 0; m < 4; ++m)
            a[m] = *(const short8*)&As[(wr + m * 16 + (lane & 15)) * 32 + (lane >> 4) * 8];
        #pragma unroll
        for (int n = 0; n < 4; ++n)
            b[n] = *(const short8*)&Bs[(wc + n * 16 + (lane & 15)) * 32 + (lane >> 4) * 8];
        #pragma unroll
        for (int m = 0; m < 4; ++m)
            #pragma unroll
            for (int n = 0; n < 4; ++n)
                acc[m][n] = __builtin_amdgcn_mfma_f32_16x16x32_bf16(a[m], b[n], acc[m][n], 0, 0, 0);
        if (t + 1 < nt) __builtin_amdgcn_s_barrier();
    }
#undef STAGE_C

    // direct epilogue: C/D layout col=lane&15, row=(lane>>4)*4+reg
    #pragma unroll
    for (int n = 0; n < 4; ++n) {
        int col = col0 + wc + n * 16 + (lane & 15);   // local col 0..255
        float bb = bias ? bias[col] : 0.f;
        float s_acc = 0.f, q_acc = 0.f;
        #pragma unroll
        for (int m = 0; m < 4; ++m) {
            int rb = row0 + wr + m * 16 + (lane >> 4) * 4;
            #pragma unroll
            for (int r = 0; r < 4; ++r) {
                int row = rb + r;
                if (row < M) {
                    float v = acc[m][n][r] + bb;
                    if (relu) v = fmaxf(v, 0.f);
                    Cb[(size_t)row * ldc + col] = f2b(v);
                    s_acc += v; q_acc += v * v;
                }
            }
        }
        if (pstat) {
            s_acc += __shfl_xor(s_acc, 16); q_acc += __shfl_xor(q_acc, 16);
            s_acc += __shfl_xor(s_acc, 32); q_acc += __shfl_xor(q_acc, 32);
            if (lane < 16) {
                int cl = wc + n * 16 + (lane & 15);   // 0..127 within block
                int half = wave >> 1;                 // row-half 0/1
                sred[half * 128 + cl] = s_acc;
                sred[256 + half * 128 + cl] = q_acc;
            }
        }
    }
    if (pstat) {
        __syncthreads();
        int c = tid & 127, which = tid >> 7;          // which: 0=sum, 1=sumsq
        float v = sred[which * 256 + c] + sred[which * 256 + 128 + c];   // fixed order: half0+half1
        size_t gcol = (size_t)(colbase + col0 + c);
        pstat[(which ? (size_t)NRB * 768 : 0) + (size_t)blockIdx.x * 768 + gcol] = v;
    }
}

// ---------------- z-batched independent GEMMs: z=0 GAT, z=1 GCN (K=128), z=2 GIN2 (K=256) ----------------
__global__ __launch_bounds__(256) void mm_gemm3(
    const ushort* __restrict__ aggb, const ushort* __restrict__ hid_b,
    const ushort* __restrict__ wt_gat, const ushort* __restrict__ wt_gcn, const ushort* __restrict__ wt_gin2,
    const float* __restrict__ b_gat, const float* __restrict__ b_gcn, const float* __restrict__ b_gin2,
    float* __restrict__ pstat,
    ushort* __restrict__ xcb)
{
    __shared__ ushort lds[16384];
    __shared__ float sred[512];
    if (blockIdx.z == 0)
        gemm_core(aggb,       384, wt_gat,  b_gat,  pstat,   0,   xcb,       768, NN, 128, 0, lds, sred);
    else if (blockIdx.z == 1)
        gemm_core(aggb + 256, 384, wt_gcn,  b_gcn,  pstat,   512, xcb + 512, 768, NN, 128, 0, lds, sred);
    else
        gemm_core(hid_b,      256, wt_gin2, b_gin2, pstat,   256, xcb + 256, 768, NN, 256, 0, lds, sred);
}

// ---------------- generic pipelined GEMM (gin1) ----------------
__global__ __launch_bounds__(256) void mm_gemm_bf(
    const ushort* __restrict__ A, int lda, const ushort* __restrict__ Bt,
    const float* __restrict__ bias, float* __restrict__ pstat, int colbase,
    ushort* __restrict__ Cb, int ldc, int M, int K, int relu)
{
    __shared__ ushort lds[16384];
    __shared__ float sred[512];
    gemm_core(A, lda, Bt, bias, pstat, colbase, Cb, ldc, M, K, relu, lds, sred);
}

// ---------------- BN+ReLU transform (sc/sh from LDS) ----------------
__device__ __forceinline__ uint4 bn_relu_pack_l(uint4 w, const float* sc, const float* sh, int c)
{
    uint4 o;
    o.x = pack2(fmaxf(b2f_lo(w.x) * sc[c + 0] + sh[c + 0], 0.f), fmaxf(b2f_hi(w.x) * sc[c + 1] + sh[c + 1], 0.f));
    o.y = pack2(fmaxf(b2f_lo(w.y) * sc[c + 2] + sh[c + 2], 0.f), fmaxf(b2f_hi(w.y) * sc[c + 3] + sh[c + 3], 0.f));
    o.z = pack2(fmaxf(b2f_lo(w.z) * sc[c + 4] + sh[c + 4], 0.f), fmaxf(b2f_hi(w.z) * sc[c + 5] + sh[c + 5], 0.f));
    o.w = pack2(fmaxf(b2f_lo(w.w) * sc[c + 6] + sh[c + 6], 0.f), fmaxf(b2f_hi(w.w) * sc[c + 7] + sh[c + 7], 0.f));
    return o;
}

// ---------------- head GEMM, pipelined: BN+ReLU fused A reg-staging, B via global_load_lds ----------------
__global__ __launch_bounds__(256) void mm_gemm_bn(
    const ushort* __restrict__ A, const ushort* __restrict__ Bt,
    const float* __restrict__ bias,
    const float* __restrict__ sc, const float* __restrict__ sh,
    ushort* __restrict__ Cb, int ldc, int M)
{
    const int K = 768, lda = 768;
    __shared__ ushort lds[16384];
    __shared__ float sc_l[768], sh_l[768];
    const int tid = threadIdx.x;
    for (int i = tid; i < 768; i += 256) { sc_l[i] = sc[i]; sh_l[i] = sh[i]; }

    const int wave = tid >> 6, lane = tid & 63;
    const int row0 = blockIdx.x * 128;
    const int col0 = blockIdx.y * 128;

    int arow0 = min(row0 + wave * 16 + (lane >> 2), M - 1);
    int arow1 = min(row0 + 64 + wave * 16 + (lane >> 2), M - 1);
    int brow0 = col0 + wave * 16 + (lane >> 2);
    int brow1 = col0 + 64 + wave * 16 + (lane >> 2);
    const ushort* pa0 = A + (size_t)arow0 * lda + (lane & 3) * 8;
    const ushort* pa1 = A + (size_t)arow1 * lda + (lane & 3) * 8;
    const ushort* pb0 = Bt + (size_t)brow0 * K + (lane & 3) * 8;
    const ushort* pb1 = Bt + (size_t)brow1 * K + (lane & 3) * 8;
    const int wr = (wave >> 1) * 64, wc = (wave & 1) * 64;

    f32x4 zero = {0.f, 0.f, 0.f, 0.f};
    f32x4 acc[4][4];
    #pragma unroll
    for (int m = 0; m < 4; ++m)
        #pragma unroll
        for (int n = 0; n < 4; ++n) acc[m][n] = zero;

    const int nt = K >> 5;   // 24

#define STAGE_B(bufi) { \
    ushort* Lb = lds + (bufi) * 8192; \
    __builtin_amdgcn_global_load_lds((const __attribute__((address_space(1))) void*)pb0, \
        (__attribute__((address_space(3))) void*)(Lb + 4096 + wave * 512), 16, 0, 0); \
    __builtin_amdgcn_global_load_lds((const __attribute__((address_space(1))) void*)pb1, \
        (__attribute__((address_space(3))) void*)(Lb + 6144 + wave * 512), 16, 0, 0); \
    pb0 += 32; pb1 += 32; }

    // prologue: tile 0 (full drain once; also covers sc_l/sh_l staging)
    uint4 w0 = *(const uint4*)pa0, w1 = *(const uint4*)pa1;
    pa0 += 32; pa1 += 32;
    STAGE_B(0);
    __syncthreads();
    {
        int c = (lane & 3) * 8;
        *(uint4*)(lds + wave * 512 + lane * 8) = bn_relu_pack_l(w0, sc_l, sh_l, c);
        *(uint4*)(lds + 2048 + wave * 512 + lane * 8) = bn_relu_pack_l(w1, sc_l, sh_l, c);
    }

    for (int t = 0; t < nt; ++t) {
        int cur = t & 1;
        bool more = (t + 1 < nt);
        uint4 w0n, w1n;
        if (more) {
            w0n = *(const uint4*)pa0; w1n = *(const uint4*)pa1;   // A-reg loads FIRST (oldest)
            pa0 += 32; pa1 += 32;
            STAGE_B(cur ^ 1);
            asm volatile("s_waitcnt vmcnt(4) lgkmcnt(0)" ::: "memory");
        } else {
            asm volatile("s_waitcnt vmcnt(0) lgkmcnt(0)" ::: "memory");
        }
        __builtin_amdgcn_s_barrier();
        const ushort* As = lds + cur * 8192;
        const ushort* Bs = As + 4096;
        short8 a[4], b[4];
        #pragma unroll
        for (int m = 0; m < 4; ++m)
            a[m] = *(const short8*)&As[(wr + m * 16 + (lane & 15)) * 32 + (lane >> 4) * 8];
        #pragma unroll
        for (int n = 0; n < 4; ++n)
            b[n] = *(const short8*)&Bs[(wc + n * 16 + (lane & 15)) * 32 + (lane >> 4) * 8];
        #pragma unroll
        for (int m = 0; m < 4; ++m)
            #pragma unroll
            for (int n = 0; n < 4; ++n)
                acc[m][n] = __builtin_amdgcn_mfma_f32_16x16x32_bf16(a[m], b[n], acc[m][n], 0, 0, 0);
        if (more) {
            int c = (t + 1) * 32 + (lane & 3) * 8;
            ushort* Ln = lds + (cur ^ 1) * 8192;
            *(uint4*)(Ln + wave * 512 + lane * 8) = bn_relu_pack_l(w0n, sc_l, sh_l, c);
            *(uint4*)(Ln + 2048 + wave * 512 + lane * 8) = bn_relu_pack_l(w1n, sc_l, sh_l, c);
            __builtin_amdgcn_s_barrier();
        }
    }
#undef STAGE_B

    #pragma unroll
    for (int n = 0; n < 4; ++n) {
        int col = col0 + wc + n * 16 + (lane & 15);
        float bb = bias[col];
        #pragma unroll
        for (int m = 0; m < 4; ++m) {
            int rb = row0 + wr + m * 16 + (lane >> 4) * 4;
            #pragma unroll
            for (int r = 0; r < 4; ++r) {
                int row = rb + r;
                if (row < M)
                    Cb[(size_t)row * ldc + col] = f2b(fmaxf(acc[m][n][r] + bb, 0.f));
            }
        }
    }
}

// reduce per-rowblock partials in fixed serial order -> deterministic BN scale/shift
__global__ void mm_bn_fin(const float* __restrict__ pstat, const float* __restrict__ gamma,
                          const float* __restrict__ beta,
                          float* __restrict__ scale, float* __restrict__ shift)
{
    int c = blockIdx.x * 256 + threadIdx.x;
    if (c >= 768) return;
    const float* ps = pstat + c;
    const float* pq = pstat + (size_t)NRB * 768 + c;
    float s = 0.f, q = 0.f;
    for (int rb = 0; rb < NRB; ++rb) {
        s += ps[(size_t)rb * 768];
        q += pq[(size_t)rb * 768];
    }
    float invn = 1.f / (float)NN;
    float mu = s * invn;
    float ex2 = q * invn;
    float var = fmaxf(ex2 - mu * mu, 0.f);
    float rs = rsqrtf(var + 1e-5f);
    float sc = gamma[c] * rs;
    scale[c] = sc;
    shift[c] = beta[c] - mu * sc;
}

// ---------------- out = h2 @ W2 + b2 (h2 bf16 [NN,256], W2 fp32 [256,40]) ----------------
__global__ __launch_bounds__(256) void mm_head2(const ushort* __restrict__ h2b, const float* __restrict__ W2,
                                                const float* __restrict__ b2, float* __restrict__ out)
{
    __shared__ float Ws[256 * 40];
    for (int i = threadIdx.x; i < 256 * 40; i += 256) Ws[i] = W2[i];
    __syncthreads();
    int row = blockIdx.x * 32 + (threadIdx.x >> 3);
    int cg = (threadIdx.x & 7) * 5;
    if (row >= NN) return;
    const ushort* hr = h2b + (size_t)row * 256;
    float acc[5] = {0, 0, 0, 0, 0};
    for (int k = 0; k < 256; k += 8) {
        uint4 w = *(const uint4*)(hr + k);
        float a0 = b2f_lo(w.x), a1 = b2f_hi(w.x), a2 = b2f_lo(w.y), a3 = b2f_hi(w.y);
        float a4 = b2f_lo(w.z), a5 = b2f_hi(w.z), a6 = b2f_lo(w.w), a7 = b2f_hi(w.w);
        #pragma unroll
        for (int j = 0; j < 5; ++j) {
            acc[j] += a0 * Ws[(k + 0) * 40 + cg + j] + a1 * Ws[(k + 1) * 40 + cg + j]
                    + a2 * Ws[(k + 2) * 40 + cg + j] + a3 * Ws[(k + 3) * 40 + cg + j]
                    + a4 * Ws[(k + 4) * 40 + cg + j] + a5 * Ws[(k + 5) * 40 + cg + j]
                    + a6 * Ws[(k + 6) * 40 + cg + j] + a7 * Ws[(k + 7) * 40 + cg + j];
        }
    }
    #pragma unroll
    for (int j = 0; j < 5; ++j) out[(size_t)row * 40 + cg + j] = acc[j] + b2[cg + j];
}

extern "C" void kernel_launch(void* const* d_in, const int* in_sizes, int n_in,
                              void* d_out, int out_size, void* d_ws, size_t ws_size,
                              hipStream_t stream)
{
    const float* x      = (const float*)d_in[0];
    const int*   ei     = (const int*)d_in[1];
    const float* W_gat  = (const float*)d_in[2];
    const float* att_s  = (const float*)d_in[3];
    const float* att_d  = (const float*)d_in[4];
    const float* b_gat  = (const float*)d_in[5];
    const float* W_gin1 = (const float*)d_in[6];
    const float* b_gin1 = (const float*)d_in[7];
    const float* W_gin2 = (const float*)d_in[8];
    const float* b_gin2 = (const float*)d_in[9];
    const float* W_gcn  = (const float*)d_in[10];
    const float* b_gcn  = (const float*)d_in[11];
    const float* gamma  = (const float*)d_in[12];
    const float* beta   = (const float*)d_in[13];
    const float* W_lin  = (const float*)d_in[14];
    const float* b_lin  = (const float*)d_in[15];
    const float* W_lin2 = (const float*)d_in[16];
    const float* b_lin2 = (const float*)d_in[17];
    const int* src = ei;
    const int* dst = ei + NE;
    float* out = (float*)d_out;

    float* ws = (float*)d_ws;
    size_t off = 0;
    ushort* xb      = (ushort*)(ws + off); off += (size_t)NN * 64;    // [NN][128] bf16
    ushort* aggb    = (ushort*)(ws + off); off += (size_t)NN * 192;   // [NN][384] bf16: gat|gin|gcn
    ushort* hid_b   = (ushort*)(ws + off); off += (size_t)NN * 128;   // GIN hidden; later h2
    ushort* xcb     = (ushort*)(ws + off); off += (size_t)NN * 384;   // [NN][768] bf16
    float* es       = ws + off; off += NN;
    float* ed       = ws + off; off += NN;
    float* dis      = ws + off; off += NN;
    float* va       = ws + off; off += 128;
    float* vd       = ws + off; off += 128;
    float* pstat    = ws + off; off += (size_t)1536 * NRB;   // BN partials: [NRB][768] sum | [NRB][768] sumsq
    float* bscale   = ws + off; off += 768;
    float* bshift   = ws + off; off += 768;
    ushort* wt_gat  = (ushort*)(ws + off); off += 128 * 256 / 2;
    ushort* wt_gin1 = (ushort*)(ws + off); off += 128 * 256 / 2;
    ushort* wt_gin2 = (ushort*)(ws + off); off += 256 * 256 / 2;
    ushort* wt_gcn  = (ushort*)(ws + off); off += 128 * 256 / 2;
    ushort* wt_lin  = (ushort*)(ws + off); off += 768 * 256 / 2;
    int* part       = (int*)(ws + off); off += 256;
    int* row_ptr    = (int*)(ws + off); off += NN + 1;
    int* cursor     = (int*)(ws + off); off += NN;
    int* csr_src    = (int*)(ws + off); off += NE;

    dim3 blk(256);
    dim3 gemm_grid(NRB, 2);       // BM=128 -> 391 row blocks, 2 col blocks
    dim3 gemm_grid3(NRB, 2, 3);   // GAT | GCN | GIN2 batched (independent)
    const int NB = (NN + 255) / 256;           // scan tiles

    // ---- zero cursor early (pstat needs no memset: every slot written exactly once) ----
    hipMemsetAsync(cursor, 0, NN * sizeof(int), stream);

    // ---- weight transposes (one launch) / attention vectors ----
    mm_wt_all<<<(360448 + 255) / 256, blk, 0, stream>>>(W_gat, W_gin1, W_gin2, W_gcn, W_lin,
                                                        wt_gat, wt_gin1, wt_gin2, wt_gcn, wt_lin);
    mm_attvec<<<1, blk, 0, stream>>>(W_gat, att_s, att_d, va, vd);

    // ---- fused convert + attention dots ----
    mm_cvt_es<<<(NN + 3) / 4, blk, 0, stream>>>(x, va, vd, xb, es, ed);

    // ---- CSR build ----
    mm_count<<<(NE + 255) / 256, blk, 0, stream>>>(dst, cursor);
    mm_scan1<<<NB, blk, 0, stream>>>(cursor, part);
    mm_scan2<<<1, blk, 0, stream>>>(part, NB);
    mm_scan3<<<NB, blk, 0, stream>>>(cursor, part, row_ptr, cursor);
    mm_dis<<<(NN + 255) / 256, blk, 0, stream>>>(row_ptr, dis);
    mm_fill<<<(NE + 255) / 256, blk, 0, stream>>>(src, dst, cursor, csr_src);

    // ---- fused per-node sort + softmax + 3-way gather ----
    mm_node_agg<<<(NN + 3) / 4, blk, 0, stream>>>(row_ptr, csr_src, es, ed, dis, xb, aggb);

    // ---- gin1 first (alone), then {GAT, GCN, GIN2} z-batched (all independent; BN partials fused) ----
    mm_gemm_bf<<<gemm_grid, blk, 0, stream>>>(aggb + 128, 384, wt_gin1, b_gin1, nullptr, 0,
                                              hid_b, 256, NN, 128, 1);
    mm_gemm3<<<gemm_grid3, blk, 0, stream>>>(aggb, hid_b, wt_gat, wt_gcn, wt_gin2,
                                             b_gat, b_gcn, b_gin2, pstat, xcb);

    // ---- BN scale/shift (deterministic serial reduce) ----
    mm_bn_fin<<<3, blk, 0, stream>>>(pstat, gamma, beta, bscale, bshift);

    // ---- head: BN+ReLU fused into A staging (pipelined) ----
    mm_gemm_bn<<<gemm_grid, blk, 0, stream>>>(xcb, wt_lin, b_lin, bscale, bshift, hid_b, 256, NN);
    mm_head2<<<(NN + 31) / 32, blk, 0, stream>>>(hid_b, W_lin2, b_lin2, out);
}